// Round 1
// baseline (193.266 us; speedup 1.0000x reference)
//
#include <hip/hip_runtime.h>
#include <math.h>

#define PAD_ID 12975
#define BB 256
#define SS 200
#define DD 1024
#define HH 16

// ws layout:
//   [0, 1024)              : int first[256]
//   [1024, 1024+819200)    : float posT[200*1024]
#define WS_FIRST_BYTES 1024
#define WS_POST_BYTES  (SS * DD * 4)

// ---------- kernel 1: first pad index per batch row ----------
__global__ void first_kernel(const int* __restrict__ x, int* __restrict__ first) {
    __shared__ int sfirst;
    const int b = blockIdx.x;
    if (threadIdx.x == 0) sfirst = SS - 1;   // no-pad => S-1 (reference semantics)
    __syncthreads();
    const int s = threadIdx.x;
    if (s < SS) {
        if (x[b * SS + s] == PAD_ID) atomicMin(&sfirst, s);
    }
    __syncthreads();
    if (threadIdx.x == 0) first[b] = sfirst;
}

// ---------- kernel 2: sinusoid table (one-time 800KB, accurate trig) ----------
__global__ void postable_kernel(float* __restrict__ posT) {
    const int idx = blockIdx.x * blockDim.x + threadIdx.x;
    if (idx >= SS * DD) return;
    const int s = idx >> 10;          // / 1024
    const int j = idx & (DD - 1);
    const int p = j >> 1;
    // denom = 10000^(p/512) = exp2(p * log2(10000)/512)
    const float C = (float)(13.287712379549449 / 512.0);
    const float denom = exp2f((float)p * C);
    const float angle = (float)s / denom;   // division, matching reference order
    posT[idx] = (j & 1) ? cosf(angle) : sinf(angle);
}

// ---------- kernel 3: mask fill, one float4 per iteration ----------
// mask[b,h,i,j] = (x[b,j]==PAD) || (i >= first[b]) ? 1.0f : 0.0f
__global__ void mask_kernel(const int* __restrict__ x, const int* __restrict__ first,
                            float* __restrict__ mask) {
    const int total = BB * HH * SS * (SS / 4);   // 40,960,000 float4 chunks
    const int stride = gridDim.x * blockDim.x;
    for (int c = blockIdx.x * blockDim.x + threadIdx.x; c < total; c += stride) {
        const int row = c / 50;              // 50 float4 per S=200 row
        const int j4  = c - row * 50;
        const int b   = row / (HH * SS);     // /3200
        const int i   = row % SS;
        float4 v;
        if (i >= first[b]) {
            v = make_float4(1.f, 1.f, 1.f, 1.f);
        } else {
            const int4 xv = ((const int4*)x)[b * 50 + j4];   // L2-hot, 204KB total
            v.x = (xv.x == PAD_ID) ? 1.f : 0.f;
            v.y = (xv.y == PAD_ID) ? 1.f : 0.f;
            v.z = (xv.z == PAD_ID) ? 1.f : 0.f;
            v.w = (xv.w == PAD_ID) ? 1.f : 0.f;
        }
        ((float4*)mask)[c] = v;
    }
}

// ---------- kernel 4: out = weight[x] + posT, table path ----------
__global__ void out_kernel(const int* __restrict__ x, const float* __restrict__ weight,
                           const float* __restrict__ posT, float* __restrict__ out) {
    const int row = blockIdx.x;          // b*S + s
    const int s = row % SS;
    const int idx = x[row];              // uniform per block
    const int t = threadIdx.x;           // 0..255, one float4 each
    const float4 w  = ((const float4*)(weight + (size_t)idx * DD))[t];
    const float4 pe = ((const float4*)(posT + (size_t)s * DD))[t];
    ((float4*)(out + (size_t)row * DD))[t] =
        make_float4(w.x + pe.x, w.y + pe.y, w.z + pe.z, w.w + pe.w);
}

// ---------- kernel 4b: fallback if ws too small for the table ----------
__global__ void out_kernel_inline(const int* __restrict__ x, const float* __restrict__ weight,
                                  float* __restrict__ out) {
    const int row = blockIdx.x;
    const int s = row % SS;
    const int idx = x[row];
    const int t = threadIdx.x;
    const float C = (float)(13.287712379549449 / 512.0);
    const float p0 = (float)(2 * t);
    const float p1 = (float)(2 * t + 1);
    const float a0 = (float)s / exp2f(p0 * C);
    const float a1 = (float)s / exp2f(p1 * C);
    const float4 pe = make_float4(sinf(a0), cosf(a0), sinf(a1), cosf(a1));
    const float4 w = ((const float4*)(weight + (size_t)idx * DD))[t];
    ((float4*)(out + (size_t)row * DD))[t] =
        make_float4(w.x + pe.x, w.y + pe.y, w.z + pe.z, w.w + pe.w);
}

extern "C" void kernel_launch(void* const* d_in, const int* in_sizes, int n_in,
                              void* d_out, int out_size, void* d_ws, size_t ws_size,
                              hipStream_t stream) {
    const int*   x      = (const int*)d_in[0];
    const float* weight = (const float*)d_in[1];
    float* out  = (float*)d_out;
    float* mask = out + (size_t)BB * SS * DD;   // outputs concatenated: (out, mask)

    int*   first = (int*)d_ws;
    float* posT  = (float*)((char*)d_ws + WS_FIRST_BYTES);
    const bool useTable = ws_size >= (size_t)(WS_FIRST_BYTES + WS_POST_BYTES);

    first_kernel<<<BB, 256, 0, stream>>>(x, first);
    if (useTable) {
        postable_kernel<<<(SS * DD + 255) / 256, 256, 0, stream>>>(posT);
    }
    mask_kernel<<<8192, 256, 0, stream>>>(x, first, mask);
    if (useTable) {
        out_kernel<<<BB * SS, 256, 0, stream>>>(x, weight, posT, out);
    } else {
        out_kernel_inline<<<BB * SS, 256, 0, stream>>>(x, weight, out);
    }
}

// Round 3
// 160.979 us; speedup vs baseline: 1.2006x; 1.2006x over previous
//
#include <hip/hip_runtime.h>
#include <math.h>

#define PAD_ID 12975
#define BB 256
#define SS 200
#define DD 1024
#define HH 16

#define MASK_CHUNKS (BB * HH * SS * (SS / 4))   // 40,960,000 float4 chunks
#define OUT_ROWS    (BB * SS)                   // 51,200 rows of 1024 floats

#define NBLK 2048      // total blocks in work kernel (full occupancy target)
#define MBLK 1376      // blocks on mask partition (655MB) vs out partition (~314MB)

// clang vector type — __builtin_nontemporal_store requires a true vector type,
// not HIP's float4 class.
typedef float f32x4 __attribute__((ext_vector_type(4)));
typedef int   i32x4 __attribute__((ext_vector_type(4)));

// ws layout: [0,1024): int first[256]; [1024, 1024+819200): float posT[200*1024]
#define WS_FIRST_BYTES 1024
#define WS_POST_BYTES  (SS * DD * 4)

// ---------- prep: sinusoid table + first-pad index, one launch ----------
__global__ void prep_kernel(const int* __restrict__ x, int* __restrict__ first,
                            float* __restrict__ posT) {
    const int idx = blockIdx.x * blockDim.x + threadIdx.x;
    if (idx < SS * DD) {
        const int s = idx >> 10;           // /1024
        const int j = idx & (DD - 1);
        const int p = j >> 1;
        const float C = (float)(13.287712379549449 / 512.0);  // log2(10000)/512
        const float angle = (float)s / exp2f((float)p * C);
        posT[idx] = (j & 1) ? cosf(angle) : sinf(angle);
    }
    // blocks 0..255 additionally compute first[b] (200 ints, L2-hot)
    if (blockIdx.x < BB) {
        __shared__ int sfirst;
        if (threadIdx.x == 0) sfirst = SS - 1;   // no-pad => S-1 (reference semantics)
        __syncthreads();
        if (threadIdx.x < SS && x[blockIdx.x * SS + threadIdx.x] == PAD_ID)
            atomicMin(&sfirst, threadIdx.x);
        __syncthreads();
        if (threadIdx.x == 0) first[blockIdx.x] = sfirst;
    }
}

// ---------- work: mask fill (blocks < MBLK) + embedding gather (rest) ----------
__global__ void work_kernel(const int* __restrict__ x, const int* __restrict__ first,
                            const float* __restrict__ weight, const float* __restrict__ posT,
                            float* __restrict__ out, float* __restrict__ mask) {
    if (blockIdx.x < MBLK) {
        // mask[b,h,i,j] = (x[b,j]==PAD) || (i>=first[b]) ? 1 : 0 — pure streaming write
        const int stride = MBLK * 256;
        for (int c = blockIdx.x * 256 + threadIdx.x; c < MASK_CHUNKS; c += stride) {
            const int row = c / 50;              // 50 float4 per S=200 row
            const int j4  = c - row * 50;
            const int b   = row / (HH * SS);     // /3200
            const int i   = row % SS;
            f32x4 v;
            if (i >= first[b]) {
                v = (f32x4){1.f, 1.f, 1.f, 1.f};
            } else {
                const i32x4 xv = ((const i32x4*)x)[b * 50 + j4];   // 204KB total, cache-hot
                v.x = (xv.x == PAD_ID) ? 1.f : 0.f;
                v.y = (xv.y == PAD_ID) ? 1.f : 0.f;
                v.z = (xv.z == PAD_ID) ? 1.f : 0.f;
                v.w = (xv.w == PAD_ID) ? 1.f : 0.f;
            }
            __builtin_nontemporal_store(v, (f32x4*)mask + c);
        }
    } else {
        // out[row,:] = weight[x[row],:] + posT[row%S,:] — one full row per iteration
        const int ob = blockIdx.x - MBLK;
        const int OB = NBLK - MBLK;
        for (int row = ob; row < OUT_ROWS; row += OB) {
            const int s   = row % SS;
            const int idx = x[row];              // wave-uniform broadcast
            const int t   = threadIdx.x;         // 256 threads × float4 = 1024 floats
            const f32x4 w  = ((const f32x4*)(weight + (size_t)idx * DD))[t];
            const f32x4 pe = ((const f32x4*)(posT + (size_t)s * DD))[t];
            const f32x4 r = w + pe;
            __builtin_nontemporal_store(r, (f32x4*)(out + (size_t)row * DD) + t);
        }
    }
}

extern "C" void kernel_launch(void* const* d_in, const int* in_sizes, int n_in,
                              void* d_out, int out_size, void* d_ws, size_t ws_size,
                              hipStream_t stream) {
    const int*   x      = (const int*)d_in[0];
    const float* weight = (const float*)d_in[1];
    float* out  = (float*)d_out;
    float* mask = out + (size_t)BB * SS * DD;   // outputs concatenated: (out, mask)

    int*   first = (int*)d_ws;
    float* posT  = (float*)((char*)d_ws + WS_FIRST_BYTES);

    prep_kernel<<<(SS * DD + 255) / 256, 256, 0, stream>>>(x, first, posT);
    work_kernel<<<NBLK, 256, 0, stream>>>(x, first, weight, posT, out, mask);
}